// Round 4
// baseline (793.754 us; speedup 1.0000x reference)
//
#include <hip/hip_runtime.h>

#define D_FEAT 128
#define BSH    8      // 256 target-nodes per bucket
#define BNODES 256
#define MAXNB  400    // supports n <= 102400
#define DB     24     // LDS staging depth per bucket (pass-1 per-bucket mean ~8)
#define CAPB   5120   // global per-bucket capacity (mean ~4092, 11 sigma slack)
#define P1B    512    // pass-1 blocks

// z[i] = (x[i,:]·w[0,:], x[i,:]·w[1,:])  — one 64-lane wave per node.
__global__ __launch_bounds__(256) void k_matvec(const float* __restrict__ x,
                                                const float* __restrict__ w,
                                                float2* __restrict__ z, int n) {
    int wave = (int)((blockIdx.x * blockDim.x + threadIdx.x) >> 6);
    int lane = threadIdx.x & 63;
    if (wave >= n) return;
    const float2 xv = *(const float2*)(x + (size_t)wave * D_FEAT + 2 * lane);
    const float2 w0 = *(const float2*)(w + 2 * lane);
    const float2 w1 = *(const float2*)(w + D_FEAT + 2 * lane);
    float p0 = xv.x * w0.x + xv.y * w0.y;
    float p1 = xv.x * w1.x + xv.y * w1.y;
    #pragma unroll
    for (int off = 32; off > 0; off >>= 1) {
        p0 += __shfl_down(p0, off, 64);
        p1 += __shfl_down(p1, off, 64);
    }
    if (lane == 0) z[wave] = make_float2(p0, p1);
}

// Pass 1: LDS-staged multisplit of edges into per-target-range buckets.
// Payload: (row << BSH) | (col & (BNODES-1))  — fits 17+8=25 bits.
__global__ __launch_bounds__(256) void k_bucket(const int* __restrict__ row,
                                                const int* __restrict__ col,
                                                unsigned* __restrict__ gcur,
                                                unsigned* __restrict__ gbuf,
                                                int E, int NB) {
    __shared__ unsigned lbuf[MAXNB * DB];
    __shared__ unsigned lcnt[MAXNB];
    const int tid = threadIdx.x;
    for (int i = tid; i < NB; i += 256) lcnt[i] = 0;
    __syncthreads();

    const int chunk = (E + P1B - 1) / P1B;
    const int s = blockIdx.x * chunk;
    const int e_end = min(s + chunk, E);
    for (int e = s + tid; e < e_end; e += 256) {
        int r = row[e], c = col[e];
        int b = c >> BSH;
        unsigned packed = ((unsigned)r << BSH) | (unsigned)(c & (BNODES - 1));
        unsigned pos = atomicAdd(&lcnt[b], 1u);
        if (pos < DB) {
            lbuf[b * DB + pos] = packed;
        } else {  // rare overflow: direct scattered store (correct, slow path)
            unsigned gp = atomicAdd(&gcur[b], 1u);
            if (gp < CAPB) gbuf[(size_t)b * CAPB + gp] = packed;
        }
    }
    __syncthreads();

    // wave-cooperative flush: one atomic + one contiguous wave-store per bucket
    const int wid = tid >> 6, lane = tid & 63;
    for (int b = wid; b < NB; b += 4) {
        unsigned cnt = lcnt[b];
        if (cnt == 0) continue;
        if (cnt > DB) cnt = DB;  // overflow entries already written directly
        unsigned gp = 0;
        if (lane == 0) gp = atomicAdd(&gcur[b], cnt);
        gp = __shfl(gp, 0, 64);
        unsigned idx = gp + (unsigned)lane;
        if ((unsigned)lane < cnt && idx < CAPB)
            gbuf[(size_t)b * CAPB + idx] = lbuf[b * DB + lane];
    }
}

// Per-bucket degree histogram in LDS -> dinv = rsqrt(deg+1); zd = z*dinv.
__global__ __launch_bounds__(256) void k_degdinv(const unsigned* __restrict__ gcur,
                                                 const unsigned* __restrict__ gbuf,
                                                 const float2* __restrict__ z,
                                                 float* __restrict__ dinv,
                                                 float2* __restrict__ zd, int n) {
    __shared__ unsigned hist[BNODES];
    const int b = blockIdx.x, tid = threadIdx.x;
    hist[tid] = 0;
    __syncthreads();
    unsigned m = gcur[b]; if (m > CAPB) m = CAPB;
    const unsigned* p = gbuf + (size_t)b * CAPB;
    for (unsigned i = tid; i < m; i += 256)
        atomicAdd(&hist[p[i] & (BNODES - 1)], 1u);
    __syncthreads();
    int c = (b << BSH) + tid;
    if (c < n) {
        float d = rsqrtf((float)hist[tid] + 1.0f);
        dinv[c] = d;
        float2 zc = z[c];
        zd[c] = make_float2(zc.x * d, zc.y * d);
    }
}

// Middle hop: out_vd[c] = dinv[c]^2 * (vd[c] + sum_{r in N(c)} vd[r])
__global__ __launch_bounds__(256) void k_hop_mid(const unsigned* __restrict__ gcur,
                                                 const unsigned* __restrict__ gbuf,
                                                 const float* __restrict__ dinv,
                                                 const float2* __restrict__ vd,
                                                 float2* __restrict__ out_vd, int n) {
    __shared__ float accx[BNODES];
    __shared__ float accy[BNODES];
    const int b = blockIdx.x, tid = threadIdx.x;
    accx[tid] = 0.0f; accy[tid] = 0.0f;
    __syncthreads();
    unsigned m = gcur[b]; if (m > CAPB) m = CAPB;
    const unsigned* p = gbuf + (size_t)b * CAPB;
    for (unsigned i = tid; i < m; i += 256) {
        unsigned pk = p[i];
        int r  = (int)(pk >> BSH);
        int cl = (int)(pk & (BNODES - 1));
        float2 v = vd[r];
        atomicAdd(&accx[cl], v.x);
        atomicAdd(&accy[cl], v.y);
    }
    __syncthreads();
    int c = (b << BSH) + tid;
    if (c < n) {
        float d = dinv[c];
        float dd = d * d;
        float2 s = vd[c];
        out_vd[c] = make_float2((s.x + accx[tid]) * dd, (s.y + accy[tid]) * dd);
    }
}

// Final hop fused with bias + log_softmax.
__global__ __launch_bounds__(256) void k_hop_final(const unsigned* __restrict__ gcur,
                                                   const unsigned* __restrict__ gbuf,
                                                   const float* __restrict__ dinv,
                                                   const float2* __restrict__ vd,
                                                   const float* __restrict__ bias,
                                                   float2* __restrict__ out, int n) {
    __shared__ float accx[BNODES];
    __shared__ float accy[BNODES];
    const int b = blockIdx.x, tid = threadIdx.x;
    accx[tid] = 0.0f; accy[tid] = 0.0f;
    __syncthreads();
    unsigned m = gcur[b]; if (m > CAPB) m = CAPB;
    const unsigned* p = gbuf + (size_t)b * CAPB;
    for (unsigned i = tid; i < m; i += 256) {
        unsigned pk = p[i];
        int r  = (int)(pk >> BSH);
        int cl = (int)(pk & (BNODES - 1));
        float2 v = vd[r];
        atomicAdd(&accx[cl], v.x);
        atomicAdd(&accy[cl], v.y);
    }
    __syncthreads();
    int c = (b << BSH) + tid;
    if (c < n) {
        float d = dinv[c];
        float2 s = vd[c];
        float l0 = (s.x + accx[tid]) * d + bias[0];
        float l1 = (s.y + accy[tid]) * d + bias[1];
        float mx = fmaxf(l0, l1);
        float lse = mx + logf(expf(l0 - mx) + expf(l1 - mx));
        out[c] = make_float2(l0 - lse, l1 - lse);
    }
}

// ---------------- fallback (R1 scatter) path, used only if assumptions break ----

__global__ __launch_bounds__(256) void k_deg(const int* __restrict__ col,
                                             unsigned int* __restrict__ deg, int E) {
    int e = blockIdx.x * blockDim.x + threadIdx.x;
    if (e < E) atomicAdd(&deg[col[e]], 1u);
}

__global__ __launch_bounds__(256) void k_dinv_init(const unsigned int* __restrict__ deg,
                                                   float* __restrict__ dinv,
                                                   const float2* __restrict__ zin,
                                                   float2* __restrict__ yout, int n) {
    int i = blockIdx.x * blockDim.x + threadIdx.x;
    if (i < n) {
        float d = rsqrtf((float)deg[i] + 1.0f);
        dinv[i] = d;
        float2 zi = zin[i];
        float dd = d * d;
        yout[i] = make_float2(zi.x * dd, zi.y * dd);
    }
}

__global__ __launch_bounds__(256) void k_selfloop(const float* __restrict__ dinv,
                                                  const float2* __restrict__ zin,
                                                  float2* __restrict__ yout, int n) {
    int i = blockIdx.x * blockDim.x + threadIdx.x;
    if (i < n) {
        float d = dinv[i];
        float dd = d * d;
        float2 zi = zin[i];
        yout[i] = make_float2(zi.x * dd, zi.y * dd);
    }
}

__global__ __launch_bounds__(256) void k_edge(const int* __restrict__ row,
                                              const int* __restrict__ col,
                                              const float* __restrict__ dinv,
                                              const float2* __restrict__ zin,
                                              float* __restrict__ yout, int E) {
    int e = blockIdx.x * blockDim.x + threadIdx.x;
    if (e < E) {
        int r = row[e], c = col[e];
        float nr = dinv[r] * dinv[c];
        float2 zr = zin[r];
        atomicAdd(&yout[2 * c + 0], zr.x * nr);
        atomicAdd(&yout[2 * c + 1], zr.y * nr);
    }
}

__global__ __launch_bounds__(256) void k_final(const float2* __restrict__ y,
                                               const float* __restrict__ bias,
                                               float2* __restrict__ out, int n) {
    int i = blockIdx.x * blockDim.x + threadIdx.x;
    if (i < n) {
        float2 l = y[i];
        float l0 = l.x + bias[0];
        float l1 = l.y + bias[1];
        float m = fmaxf(l0, l1);
        float lse = m + logf(expf(l0 - m) + expf(l1 - m));
        out[i] = make_float2(l0 - lse, l1 - lse);
    }
}

extern "C" void kernel_launch(void* const* d_in, const int* in_sizes, int n_in,
                              void* d_out, int out_size, void* d_ws, size_t ws_size,
                              hipStream_t stream) {
    const float* x    = (const float*)d_in[0];
    const int*   ei   = (const int*)d_in[1];
    const float* w    = (const float*)d_in[2];
    const float* bias = (const float*)d_in[3];

    const int n = in_sizes[0] / D_FEAT;   // 100000
    const int E = in_sizes[1] / 2;        // 1600000
    const int* row = ei;       // edge_index[0] = source
    const int* col = ei + E;   // edge_index[1] = target

    const int TB = 256;
    const int nodeBlocks = (n + TB - 1) / TB;
    const int edgeBlocks = (E + TB - 1) / TB;
    const int waveBlocks = (n + 3) / 4;

    const int NB = (n + BNODES - 1) >> BSH;  // 391 for n=100000
    size_t needBucket = (size_t)NB * CAPB * 4 + (size_t)n * (3 * sizeof(float2) + sizeof(float)) + 4096;

    if (NB <= MAXNB && (size_t)E <= (size_t)NB * CAPB && ws_size >= needBucket) {
        char* ws = (char*)d_ws;
        unsigned* gcur = (unsigned*)ws;      ws += 4096;  // NB counters, padded
        unsigned* gbuf = (unsigned*)ws;      ws += (size_t)NB * CAPB * 4;
        float2* z    = (float2*)ws;          ws += (size_t)n * sizeof(float2);
        float2* zd   = (float2*)ws;          ws += (size_t)n * sizeof(float2);
        float2* y1d  = (float2*)ws;          ws += (size_t)n * sizeof(float2);
        float*  dinv = (float*)ws;

        hipMemsetAsync(gcur, 0, (size_t)NB * 4, stream);
        k_bucket<<<P1B, TB, 0, stream>>>(row, col, gcur, gbuf, E, NB);
        k_matvec<<<waveBlocks, TB, 0, stream>>>(x, w, z, n);
        k_degdinv<<<NB, TB, 0, stream>>>(gcur, gbuf, z, dinv, zd, n);
        k_hop_mid<<<NB, TB, 0, stream>>>(gcur, gbuf, dinv, zd, y1d, n);
        k_hop_final<<<NB, TB, 0, stream>>>(gcur, gbuf, dinv, y1d, bias,
                                           (float2*)d_out, n);
    } else {
        // R1 fallback: atomic scatter (known-correct)
        char* ws = (char*)d_ws;
        float2* z   = (float2*)ws; ws += (size_t)n * sizeof(float2);
        float2* y1  = (float2*)ws; ws += (size_t)n * sizeof(float2);
        float2* y2  = (float2*)ws; ws += (size_t)n * sizeof(float2);
        float*  dinv = (float*)ws; ws += (size_t)n * sizeof(float);
        unsigned int* deg = (unsigned int*)ws;

        hipMemsetAsync(deg, 0, (size_t)n * sizeof(unsigned int), stream);
        k_deg<<<edgeBlocks, TB, 0, stream>>>(col, deg, E);
        k_matvec<<<waveBlocks, TB, 0, stream>>>(x, w, z, n);
        k_dinv_init<<<nodeBlocks, TB, 0, stream>>>(deg, dinv, z, y1, n);
        k_edge<<<edgeBlocks, TB, 0, stream>>>(row, col, dinv, z, (float*)y1, E);
        k_selfloop<<<nodeBlocks, TB, 0, stream>>>(dinv, y1, y2, n);
        k_edge<<<edgeBlocks, TB, 0, stream>>>(row, col, dinv, y1, (float*)y2, E);
        k_final<<<nodeBlocks, TB, 0, stream>>>(y2, bias, (float2*)d_out, n);
    }
}

// Round 5
// 183.655 us; speedup vs baseline: 4.3220x; 4.3220x over previous
//
#include <hip/hip_runtime.h>

#define D_FEAT 128
#define BSH    8              // 256 target-nodes per bucket
#define BNODES 256
#define MAXNB  400            // supports n <= 102400
#define NSEG   512            // pass-1 blocks == segments per bucket
#define SEGCAP 16             // slots per (bucket, segment): 64 B = one cache line
#define SENT   0xFFFFFFFFu    // empty-slot marker (packed values < 2^25)
#define OVCAP  (1u << 20)     // overflow list capacity (expected use ~1e3)

// z[i] = (x[i,:]·w[0,:], x[i,:]·w[1,:])  — one 64-lane wave per node.
__global__ __launch_bounds__(256) void k_matvec(const float* __restrict__ x,
                                                const float* __restrict__ w,
                                                float2* __restrict__ z, int n) {
    int wave = (int)((blockIdx.x * blockDim.x + threadIdx.x) >> 6);
    int lane = threadIdx.x & 63;
    if (wave >= n) return;
    const float2 xv = *(const float2*)(x + (size_t)wave * D_FEAT + 2 * lane);
    const float2 w0 = *(const float2*)(w + 2 * lane);
    const float2 w1 = *(const float2*)(w + D_FEAT + 2 * lane);
    float p0 = xv.x * w0.x + xv.y * w0.y;
    float p1 = xv.x * w1.x + xv.y * w1.y;
    #pragma unroll
    for (int off = 32; off > 0; off >>= 1) {
        p0 += __shfl_down(p0, off, 64);
        p1 += __shfl_down(p1, off, 64);
    }
    if (lane == 0) z[wave] = make_float2(p0, p1);
}

// Pass 1: contention-free multisplit. Block blk owns gbuf[b][blk][0..15] for
// every bucket b — no global atomics on the hot path, every slot written
// exactly once (sentinel if empty), each (b,blk) segment is one 64B line.
__global__ __launch_bounds__(256) void k_bucket(const int* __restrict__ row,
                                                const int* __restrict__ col,
                                                unsigned* __restrict__ ovcnt,
                                                unsigned long long* __restrict__ ovbuf,
                                                unsigned* __restrict__ gbuf,
                                                int E, int NB) {
    __shared__ unsigned lcnt[MAXNB];
    __shared__ unsigned lbuf[MAXNB * SEGCAP];
    const int tid = threadIdx.x;
    for (int i = tid; i < NB; i += 256) lcnt[i] = 0;
    __syncthreads();

    const int chunk = (E + NSEG - 1) / NSEG;
    const int s = blockIdx.x * chunk;
    const int e_end = min(s + chunk, E);
    for (int e = s + tid; e < e_end; e += 256) {
        int r = row[e], c = col[e];
        int b = c >> BSH;
        unsigned pos = atomicAdd(&lcnt[b], 1u);   // LDS atomic only
        if (pos < SEGCAP) {
            lbuf[b * SEGCAP + pos] = ((unsigned)r << BSH) | (unsigned)(c & (BNODES - 1));
        } else {  // statistically rare: Poisson(8) tail beyond 16
            unsigned gi = atomicAdd(ovcnt, 1u);
            if (gi < OVCAP)
                ovbuf[gi] = ((unsigned long long)(unsigned)r << 32) | (unsigned)c;
        }
    }
    __syncthreads();

    // flush: every slot of every bucket, fully coalesced 64B-line stores
    const unsigned blk = blockIdx.x;
    const int total = NB * SEGCAP;
    for (int idx = tid; idx < total; idx += 256) {
        int b = idx >> 4;        // SEGCAP == 16
        int slot = idx & 15;
        unsigned cnt = lcnt[b]; if (cnt > SEGCAP) cnt = SEGCAP;
        unsigned v = ((unsigned)slot < cnt) ? lbuf[idx] : SENT;
        gbuf[((size_t)b * NSEG + blk) * SEGCAP + slot] = v;
    }
}

// Per-bucket degree histogram -> dinv = rsqrt(deg+1); zd = z*dinv.
__global__ __launch_bounds__(256) void k_degdinv(const unsigned* __restrict__ gbuf,
                                                 const unsigned* __restrict__ ovcnt,
                                                 const unsigned long long* __restrict__ ovbuf,
                                                 const float2* __restrict__ z,
                                                 float* __restrict__ dinv,
                                                 float2* __restrict__ zd, int n) {
    __shared__ unsigned hist[BNODES];
    const int b = blockIdx.x, tid = threadIdx.x;
    hist[tid] = 0;
    __syncthreads();
    const unsigned* p = gbuf + (size_t)b * NSEG * SEGCAP;
    for (int i = tid; i < NSEG * SEGCAP; i += 256) {
        unsigned v = p[i];
        if (v != SENT) atomicAdd(&hist[v & (BNODES - 1)], 1u);
    }
    unsigned oc = *ovcnt; if (oc > OVCAP) oc = OVCAP;
    for (unsigned i = tid; i < oc; i += 256) {
        unsigned long long e = ovbuf[i];
        unsigned c = (unsigned)e;
        if ((int)(c >> BSH) == b) atomicAdd(&hist[c & (BNODES - 1)], 1u);
    }
    __syncthreads();
    int c = (b << BSH) + tid;
    if (c < n) {
        float d = rsqrtf((float)hist[tid] + 1.0f);
        dinv[c] = d;
        float2 zc = z[c];
        zd[c] = make_float2(zc.x * d, zc.y * d);
    }
}

// Middle hop: out_vd[c] = dinv[c]^2 * (vd[c] + sum_{r in N(c)} vd[r])
__global__ __launch_bounds__(256) void k_hop_mid(const unsigned* __restrict__ gbuf,
                                                 const unsigned* __restrict__ ovcnt,
                                                 const unsigned long long* __restrict__ ovbuf,
                                                 const float* __restrict__ dinv,
                                                 const float2* __restrict__ vd,
                                                 float2* __restrict__ out_vd, int n) {
    __shared__ float accx[BNODES];
    __shared__ float accy[BNODES];
    const int b = blockIdx.x, tid = threadIdx.x;
    accx[tid] = 0.0f; accy[tid] = 0.0f;
    __syncthreads();
    const unsigned* p = gbuf + (size_t)b * NSEG * SEGCAP;
    for (int i = tid; i < NSEG * SEGCAP; i += 256) {
        unsigned v = p[i];
        if (v != SENT) {
            float2 vv = vd[v >> BSH];
            int cl = (int)(v & (BNODES - 1));
            atomicAdd(&accx[cl], vv.x);
            atomicAdd(&accy[cl], vv.y);
        }
    }
    unsigned oc = *ovcnt; if (oc > OVCAP) oc = OVCAP;
    for (unsigned i = tid; i < oc; i += 256) {
        unsigned long long e = ovbuf[i];
        unsigned c = (unsigned)e;
        if ((int)(c >> BSH) == b) {
            float2 vv = vd[(unsigned)(e >> 32)];
            int cl = (int)(c & (BNODES - 1));
            atomicAdd(&accx[cl], vv.x);
            atomicAdd(&accy[cl], vv.y);
        }
    }
    __syncthreads();
    int c = (b << BSH) + tid;
    if (c < n) {
        float d = dinv[c];
        float dd = d * d;
        float2 s = vd[c];
        out_vd[c] = make_float2((s.x + accx[tid]) * dd, (s.y + accy[tid]) * dd);
    }
}

// Final hop fused with bias + log_softmax.
__global__ __launch_bounds__(256) void k_hop_final(const unsigned* __restrict__ gbuf,
                                                   const unsigned* __restrict__ ovcnt,
                                                   const unsigned long long* __restrict__ ovbuf,
                                                   const float* __restrict__ dinv,
                                                   const float2* __restrict__ vd,
                                                   const float* __restrict__ bias,
                                                   float2* __restrict__ out, int n) {
    __shared__ float accx[BNODES];
    __shared__ float accy[BNODES];
    const int b = blockIdx.x, tid = threadIdx.x;
    accx[tid] = 0.0f; accy[tid] = 0.0f;
    __syncthreads();
    const unsigned* p = gbuf + (size_t)b * NSEG * SEGCAP;
    for (int i = tid; i < NSEG * SEGCAP; i += 256) {
        unsigned v = p[i];
        if (v != SENT) {
            float2 vv = vd[v >> BSH];
            int cl = (int)(v & (BNODES - 1));
            atomicAdd(&accx[cl], vv.x);
            atomicAdd(&accy[cl], vv.y);
        }
    }
    unsigned oc = *ovcnt; if (oc > OVCAP) oc = OVCAP;
    for (unsigned i = tid; i < oc; i += 256) {
        unsigned long long e = ovbuf[i];
        unsigned c = (unsigned)e;
        if ((int)(c >> BSH) == b) {
            float2 vv = vd[(unsigned)(e >> 32)];
            int cl = (int)(c & (BNODES - 1));
            atomicAdd(&accx[cl], vv.x);
            atomicAdd(&accy[cl], vv.y);
        }
    }
    __syncthreads();
    int c = (b << BSH) + tid;
    if (c < n) {
        float d = dinv[c];
        float2 s = vd[c];
        float l0 = (s.x + accx[tid]) * d + bias[0];
        float l1 = (s.y + accy[tid]) * d + bias[1];
        float mx = fmaxf(l0, l1);
        float lse = mx + logf(expf(l0 - mx) + expf(l1 - mx));
        out[c] = make_float2(l0 - lse, l1 - lse);
    }
}

// ---------------- fallback (R1 scatter) path ----------------

__global__ __launch_bounds__(256) void k_deg(const int* __restrict__ col,
                                             unsigned int* __restrict__ deg, int E) {
    int e = blockIdx.x * blockDim.x + threadIdx.x;
    if (e < E) atomicAdd(&deg[col[e]], 1u);
}

__global__ __launch_bounds__(256) void k_dinv_init(const unsigned int* __restrict__ deg,
                                                   float* __restrict__ dinv,
                                                   const float2* __restrict__ zin,
                                                   float2* __restrict__ yout, int n) {
    int i = blockIdx.x * blockDim.x + threadIdx.x;
    if (i < n) {
        float d = rsqrtf((float)deg[i] + 1.0f);
        dinv[i] = d;
        float2 zi = zin[i];
        float dd = d * d;
        yout[i] = make_float2(zi.x * dd, zi.y * dd);
    }
}

__global__ __launch_bounds__(256) void k_selfloop(const float* __restrict__ dinv,
                                                  const float2* __restrict__ zin,
                                                  float2* __restrict__ yout, int n) {
    int i = blockIdx.x * blockDim.x + threadIdx.x;
    if (i < n) {
        float d = dinv[i];
        float dd = d * d;
        float2 zi = zin[i];
        yout[i] = make_float2(zi.x * dd, zi.y * dd);
    }
}

__global__ __launch_bounds__(256) void k_edge(const int* __restrict__ row,
                                              const int* __restrict__ col,
                                              const float* __restrict__ dinv,
                                              const float2* __restrict__ zin,
                                              float* __restrict__ yout, int E) {
    int e = blockIdx.x * blockDim.x + threadIdx.x;
    if (e < E) {
        int r = row[e], c = col[e];
        float nr = dinv[r] * dinv[c];
        float2 zr = zin[r];
        atomicAdd(&yout[2 * c + 0], zr.x * nr);
        atomicAdd(&yout[2 * c + 1], zr.y * nr);
    }
}

__global__ __launch_bounds__(256) void k_final(const float2* __restrict__ y,
                                               const float* __restrict__ bias,
                                               float2* __restrict__ out, int n) {
    int i = blockIdx.x * blockDim.x + threadIdx.x;
    if (i < n) {
        float2 l = y[i];
        float l0 = l.x + bias[0];
        float l1 = l.y + bias[1];
        float m = fmaxf(l0, l1);
        float lse = m + logf(expf(l0 - m) + expf(l1 - m));
        out[i] = make_float2(l0 - lse, l1 - lse);
    }
}

extern "C" void kernel_launch(void* const* d_in, const int* in_sizes, int n_in,
                              void* d_out, int out_size, void* d_ws, size_t ws_size,
                              hipStream_t stream) {
    const float* x    = (const float*)d_in[0];
    const int*   ei   = (const int*)d_in[1];
    const float* w    = (const float*)d_in[2];
    const float* bias = (const float*)d_in[3];

    const int n = in_sizes[0] / D_FEAT;   // 100000
    const int E = in_sizes[1] / 2;        // 1600000
    const int* row = ei;       // edge_index[0] = source
    const int* col = ei + E;   // edge_index[1] = target

    const int TB = 256;
    const int nodeBlocks = (n + TB - 1) / TB;
    const int edgeBlocks = (E + TB - 1) / TB;
    const int waveBlocks = (n + 3) / 4;

    const int NB = (n + BNODES - 1) >> BSH;  // 391 for n=100000

    size_t needSeg = 128                                      // ovcnt
                   + (size_t)OVCAP * 8                        // ovbuf
                   + (size_t)NB * NSEG * SEGCAP * 4           // gbuf (12.8 MB)
                   + (size_t)n * (3 * sizeof(float2) + sizeof(float));

    if (NB <= MAXNB && n < (1 << 24) && ws_size >= needSeg) {
        char* ws = (char*)d_ws;
        unsigned* ovcnt = (unsigned*)ws;              ws += 128;
        unsigned long long* ovbuf = (unsigned long long*)ws; ws += (size_t)OVCAP * 8;
        unsigned* gbuf = (unsigned*)ws;               ws += (size_t)NB * NSEG * SEGCAP * 4;
        float2* z    = (float2*)ws;                   ws += (size_t)n * sizeof(float2);
        float2* zd   = (float2*)ws;                   ws += (size_t)n * sizeof(float2);
        float2* y1d  = (float2*)ws;                   ws += (size_t)n * sizeof(float2);
        float*  dinv = (float*)ws;

        hipMemsetAsync(ovcnt, 0, 128, stream);
        k_bucket<<<NSEG, TB, 0, stream>>>(row, col, ovcnt, ovbuf, gbuf, E, NB);
        k_matvec<<<waveBlocks, TB, 0, stream>>>(x, w, z, n);
        k_degdinv<<<NB, TB, 0, stream>>>(gbuf, ovcnt, ovbuf, z, dinv, zd, n);
        k_hop_mid<<<NB, TB, 0, stream>>>(gbuf, ovcnt, ovbuf, dinv, zd, y1d, n);
        k_hop_final<<<NB, TB, 0, stream>>>(gbuf, ovcnt, ovbuf, dinv, y1d, bias,
                                           (float2*)d_out, n);
    } else {
        // R1 fallback: atomic scatter (known-correct)
        char* ws = (char*)d_ws;
        float2* z   = (float2*)ws; ws += (size_t)n * sizeof(float2);
        float2* y1  = (float2*)ws; ws += (size_t)n * sizeof(float2);
        float2* y2  = (float2*)ws; ws += (size_t)n * sizeof(float2);
        float*  dinv = (float*)ws; ws += (size_t)n * sizeof(float);
        unsigned int* deg = (unsigned int*)ws;

        hipMemsetAsync(deg, 0, (size_t)n * sizeof(unsigned int), stream);
        k_deg<<<edgeBlocks, TB, 0, stream>>>(col, deg, E);
        k_matvec<<<waveBlocks, TB, 0, stream>>>(x, w, z, n);
        k_dinv_init<<<nodeBlocks, TB, 0, stream>>>(deg, dinv, z, y1, n);
        k_edge<<<edgeBlocks, TB, 0, stream>>>(row, col, dinv, z, (float*)y1, E);
        k_selfloop<<<nodeBlocks, TB, 0, stream>>>(dinv, y1, y2, n);
        k_edge<<<edgeBlocks, TB, 0, stream>>>(row, col, dinv, y1, (float*)y2, E);
        k_final<<<nodeBlocks, TB, 0, stream>>>(y2, bias, (float2*)d_out, n);
    }
}

// Round 6
// 179.769 us; speedup vs baseline: 4.4154x; 1.0216x over previous
//
#include <hip/hip_runtime.h>

#define D_FEAT 128
#define BSH    8              // 256 target-nodes per bucket
#define BNODES 256
#define MAXNB  400            // supports n <= 102400
#define NSEG   512            // pass-1 blocks == segments per bucket
#define SEGCAP 16             // slots per (bucket, segment): 64 B = one cache line
#define SENT   0xFFFFFFFFu    // empty-slot marker (packed values < 2^25)
#define OVCAP  (1u << 20)     // overflow list capacity (expected use ~1e3)
#define SPLIT  4              // sub-blocks per bucket in consumer passes
#define SEGPS  (NSEG / SPLIT) // segments per sub-block (128)

// z[i] = (x[i,:]·w[0,:], x[i,:]·w[1,:])  — one 64-lane wave per node.
__global__ __launch_bounds__(256) void k_matvec(const float* __restrict__ x,
                                                const float* __restrict__ w,
                                                float2* __restrict__ z, int n) {
    int wave = (int)((blockIdx.x * blockDim.x + threadIdx.x) >> 6);
    int lane = threadIdx.x & 63;
    if (wave >= n) return;
    const float2 xv = *(const float2*)(x + (size_t)wave * D_FEAT + 2 * lane);
    const float2 w0 = *(const float2*)(w + 2 * lane);
    const float2 w1 = *(const float2*)(w + D_FEAT + 2 * lane);
    float p0 = xv.x * w0.x + xv.y * w0.y;
    float p1 = xv.x * w1.x + xv.y * w1.y;
    #pragma unroll
    for (int off = 32; off > 0; off >>= 1) {
        p0 += __shfl_down(p0, off, 64);
        p1 += __shfl_down(p1, off, 64);
    }
    if (lane == 0) z[wave] = make_float2(p0, p1);
}

// Pass 1: contention-free multisplit (unchanged from R5 — measured fast).
__global__ __launch_bounds__(256) void k_bucket(const int* __restrict__ row,
                                                const int* __restrict__ col,
                                                unsigned* __restrict__ ovcnt,
                                                unsigned long long* __restrict__ ovbuf,
                                                unsigned* __restrict__ gbuf,
                                                int E, int NB) {
    __shared__ unsigned lcnt[MAXNB];
    __shared__ unsigned lbuf[MAXNB * SEGCAP];
    const int tid = threadIdx.x;
    for (int i = tid; i < NB; i += 256) lcnt[i] = 0;
    __syncthreads();

    const int chunk = (E + NSEG - 1) / NSEG;
    const int s = blockIdx.x * chunk;
    const int e_end = min(s + chunk, E);
    for (int e = s + tid; e < e_end; e += 256) {
        int r = row[e], c = col[e];
        int b = c >> BSH;
        unsigned pos = atomicAdd(&lcnt[b], 1u);   // LDS atomic only
        if (pos < SEGCAP) {
            lbuf[b * SEGCAP + pos] = ((unsigned)r << BSH) | (unsigned)(c & (BNODES - 1));
        } else {  // rare Poisson(8) tail beyond 16 — exact overflow list
            unsigned gi = atomicAdd(ovcnt, 1u);
            if (gi < OVCAP)
                ovbuf[gi] = ((unsigned long long)(unsigned)r << 32) | (unsigned)c;
        }
    }
    __syncthreads();

    const unsigned blk = blockIdx.x;
    const int total = NB * SEGCAP;
    for (int idx = tid; idx < total; idx += 256) {
        int b = idx >> 4;
        int slot = idx & 15;
        unsigned cnt = lcnt[b]; if (cnt > SEGCAP) cnt = SEGCAP;
        unsigned v = ((unsigned)slot < cnt) ? lbuf[idx] : SENT;
        gbuf[((size_t)b * NSEG + blk) * SEGCAP + slot] = v;
    }
}

// Degree partials: sub-block (b,s) histograms its 128-segment slice.
__global__ __launch_bounds__(256) void k_deg_part(const unsigned* __restrict__ gbuf,
                                                  const unsigned* __restrict__ ovcnt,
                                                  const unsigned long long* __restrict__ ovbuf,
                                                  unsigned* __restrict__ pdeg) {
    __shared__ unsigned hist[BNODES];
    const int b = blockIdx.x >> 2, s = blockIdx.x & 3, tid = threadIdx.x;
    hist[tid] = 0;
    __syncthreads();
    const uint4* p4 = (const uint4*)(gbuf + ((size_t)b * NSEG + (size_t)s * SEGPS) * SEGCAP);
    for (int j = tid; j < SEGPS * SEGCAP / 4; j += 256) {
        uint4 v = p4[j];
        if (v.x != SENT) atomicAdd(&hist[v.x & (BNODES - 1)], 1u);
        if (v.y != SENT) atomicAdd(&hist[v.y & (BNODES - 1)], 1u);
        if (v.z != SENT) atomicAdd(&hist[v.z & (BNODES - 1)], 1u);
        if (v.w != SENT) atomicAdd(&hist[v.w & (BNODES - 1)], 1u);
    }
    if (s == 0) {
        unsigned oc = *ovcnt; if (oc > OVCAP) oc = OVCAP;
        for (unsigned i = tid; i < oc; i += 256) {
            unsigned c = (unsigned)ovbuf[i];
            if ((int)(c >> BSH) == b) atomicAdd(&hist[c & (BNODES - 1)], 1u);
        }
    }
    __syncthreads();
    pdeg[(size_t)blockIdx.x * BNODES + tid] = hist[tid];
}

// dinv = rsqrt(deg+1); zd = z*dinv.
__global__ __launch_bounds__(256) void k_deg_reduce(const unsigned* __restrict__ pdeg,
                                                    const float2* __restrict__ z,
                                                    float* __restrict__ dinv,
                                                    float2* __restrict__ zd, int n) {
    int i = blockIdx.x * blockDim.x + threadIdx.x;
    if (i >= n) return;
    int b = i >> BSH, t = i & (BNODES - 1);
    unsigned deg = 0;
    #pragma unroll
    for (int s = 0; s < SPLIT; ++s) deg += pdeg[(size_t)(b * SPLIT + s) * BNODES + t];
    float d = rsqrtf((float)deg + 1.0f);
    dinv[i] = d;
    float2 zc = z[i];
    zd[i] = make_float2(zc.x * d, zc.y * d);
}

// Hop partials: sub-block (b,s) accumulates sum of vd[r] over its slice.
__global__ __launch_bounds__(256) void k_hop_part(const unsigned* __restrict__ gbuf,
                                                  const unsigned* __restrict__ ovcnt,
                                                  const unsigned long long* __restrict__ ovbuf,
                                                  const float2* __restrict__ vd,
                                                  float2* __restrict__ pbuf) {
    __shared__ float accx[BNODES];
    __shared__ float accy[BNODES];
    const int b = blockIdx.x >> 2, s = blockIdx.x & 3, tid = threadIdx.x;
    accx[tid] = 0.0f; accy[tid] = 0.0f;
    __syncthreads();
    const uint4* p4 = (const uint4*)(gbuf + ((size_t)b * NSEG + (size_t)s * SEGPS) * SEGCAP);
    for (int j = tid; j < SEGPS * SEGCAP / 4; j += 256) {
        uint4 v = p4[j];
        if (v.x != SENT) { float2 t = vd[v.x >> BSH]; int c = v.x & (BNODES-1); atomicAdd(&accx[c], t.x); atomicAdd(&accy[c], t.y); }
        if (v.y != SENT) { float2 t = vd[v.y >> BSH]; int c = v.y & (BNODES-1); atomicAdd(&accx[c], t.x); atomicAdd(&accy[c], t.y); }
        if (v.z != SENT) { float2 t = vd[v.z >> BSH]; int c = v.z & (BNODES-1); atomicAdd(&accx[c], t.x); atomicAdd(&accy[c], t.y); }
        if (v.w != SENT) { float2 t = vd[v.w >> BSH]; int c = v.w & (BNODES-1); atomicAdd(&accx[c], t.x); atomicAdd(&accy[c], t.y); }
    }
    if (s == 0) {
        unsigned oc = *ovcnt; if (oc > OVCAP) oc = OVCAP;
        for (unsigned i = tid; i < oc; i += 256) {
            unsigned long long e = ovbuf[i];
            unsigned c = (unsigned)e;
            if ((int)(c >> BSH) == b) {
                float2 t = vd[(unsigned)(e >> 32)];
                int cl = (int)(c & (BNODES - 1));
                atomicAdd(&accx[cl], t.x);
                atomicAdd(&accy[cl], t.y);
            }
        }
    }
    __syncthreads();
    pbuf[(size_t)blockIdx.x * BNODES + tid] = make_float2(accx[tid], accy[tid]);
}

// Middle-hop reduce: out_vd[c] = dinv[c]^2 * (vd_self[c] + sum partials)
__global__ __launch_bounds__(256) void k_mid_reduce(const float2* __restrict__ pbuf,
                                                    const float2* __restrict__ vd,
                                                    const float* __restrict__ dinv,
                                                    float2* __restrict__ out_vd, int n) {
    int i = blockIdx.x * blockDim.x + threadIdx.x;
    if (i >= n) return;
    int b = i >> BSH, t = i & (BNODES - 1);
    float2 acc = vd[i];
    #pragma unroll
    for (int s = 0; s < SPLIT; ++s) {
        float2 p = pbuf[(size_t)(b * SPLIT + s) * BNODES + t];
        acc.x += p.x; acc.y += p.y;
    }
    float d = dinv[i], dd = d * d;
    out_vd[i] = make_float2(acc.x * dd, acc.y * dd);
}

// Final reduce: logits = dinv*(vd_self + sum partials) + bias; log_softmax.
__global__ __launch_bounds__(256) void k_fin_reduce(const float2* __restrict__ pbuf,
                                                    const float2* __restrict__ vd,
                                                    const float* __restrict__ dinv,
                                                    const float* __restrict__ bias,
                                                    float2* __restrict__ out, int n) {
    int i = blockIdx.x * blockDim.x + threadIdx.x;
    if (i >= n) return;
    int b = i >> BSH, t = i & (BNODES - 1);
    float2 acc = vd[i];
    #pragma unroll
    for (int s = 0; s < SPLIT; ++s) {
        float2 p = pbuf[(size_t)(b * SPLIT + s) * BNODES + t];
        acc.x += p.x; acc.y += p.y;
    }
    float d = dinv[i];
    float l0 = acc.x * d + bias[0];
    float l1 = acc.y * d + bias[1];
    float mx = fmaxf(l0, l1);
    float lse = mx + logf(expf(l0 - mx) + expf(l1 - mx));
    out[i] = make_float2(l0 - lse, l1 - lse);
}

// ---------------- fallback (R1 scatter) path ----------------

__global__ __launch_bounds__(256) void k_deg(const int* __restrict__ col,
                                             unsigned int* __restrict__ deg, int E) {
    int e = blockIdx.x * blockDim.x + threadIdx.x;
    if (e < E) atomicAdd(&deg[col[e]], 1u);
}

__global__ __launch_bounds__(256) void k_dinv_init(const unsigned int* __restrict__ deg,
                                                   float* __restrict__ dinv,
                                                   const float2* __restrict__ zin,
                                                   float2* __restrict__ yout, int n) {
    int i = blockIdx.x * blockDim.x + threadIdx.x;
    if (i < n) {
        float d = rsqrtf((float)deg[i] + 1.0f);
        dinv[i] = d;
        float2 zi = zin[i];
        float dd = d * d;
        yout[i] = make_float2(zi.x * dd, zi.y * dd);
    }
}

__global__ __launch_bounds__(256) void k_selfloop(const float* __restrict__ dinv,
                                                  const float2* __restrict__ zin,
                                                  float2* __restrict__ yout, int n) {
    int i = blockIdx.x * blockDim.x + threadIdx.x;
    if (i < n) {
        float d = dinv[i];
        float dd = d * d;
        float2 zi = zin[i];
        yout[i] = make_float2(zi.x * dd, zi.y * dd);
    }
}

__global__ __launch_bounds__(256) void k_edge(const int* __restrict__ row,
                                              const int* __restrict__ col,
                                              const float* __restrict__ dinv,
                                              const float2* __restrict__ zin,
                                              float* __restrict__ yout, int E) {
    int e = blockIdx.x * blockDim.x + threadIdx.x;
    if (e < E) {
        int r = row[e], c = col[e];
        float nr = dinv[r] * dinv[c];
        float2 zr = zin[r];
        atomicAdd(&yout[2 * c + 0], zr.x * nr);
        atomicAdd(&yout[2 * c + 1], zr.y * nr);
    }
}

__global__ __launch_bounds__(256) void k_final(const float2* __restrict__ y,
                                               const float* __restrict__ bias,
                                               float2* __restrict__ out, int n) {
    int i = blockIdx.x * blockDim.x + threadIdx.x;
    if (i < n) {
        float2 l = y[i];
        float l0 = l.x + bias[0];
        float l1 = l.y + bias[1];
        float m = fmaxf(l0, l1);
        float lse = m + logf(expf(l0 - m) + expf(l1 - m));
        out[i] = make_float2(l0 - lse, l1 - lse);
    }
}

extern "C" void kernel_launch(void* const* d_in, const int* in_sizes, int n_in,
                              void* d_out, int out_size, void* d_ws, size_t ws_size,
                              hipStream_t stream) {
    const float* x    = (const float*)d_in[0];
    const int*   ei   = (const int*)d_in[1];
    const float* w    = (const float*)d_in[2];
    const float* bias = (const float*)d_in[3];

    const int n = in_sizes[0] / D_FEAT;   // 100000
    const int E = in_sizes[1] / 2;        // 1600000
    const int* row = ei;
    const int* col = ei + E;

    const int TB = 256;
    const int nodeBlocks = (n + TB - 1) / TB;
    const int edgeBlocks = (E + TB - 1) / TB;
    const int waveBlocks = (n + 3) / 4;

    const int NB = (n + BNODES - 1) >> BSH;  // 391 for n=100000

    size_t needSeg = 128
                   + (size_t)OVCAP * 8
                   + (size_t)NB * NSEG * SEGCAP * 4
                   + (size_t)n * (3 * sizeof(float2) + sizeof(float))
                   + (size_t)NB * SPLIT * BNODES * sizeof(float2)   // pbuf
                   + (size_t)NB * SPLIT * BNODES * sizeof(unsigned);// pdeg

    if (NB <= MAXNB && n < (1 << 24) && ws_size >= needSeg) {
        char* ws = (char*)d_ws;
        unsigned* ovcnt = (unsigned*)ws;              ws += 128;
        unsigned long long* ovbuf = (unsigned long long*)ws; ws += (size_t)OVCAP * 8;
        unsigned* gbuf = (unsigned*)ws;               ws += (size_t)NB * NSEG * SEGCAP * 4;
        float2* z    = (float2*)ws;                   ws += (size_t)n * sizeof(float2);
        float2* zd   = (float2*)ws;                   ws += (size_t)n * sizeof(float2);
        float2* y1d  = (float2*)ws;                   ws += (size_t)n * sizeof(float2);
        float*  dinv = (float*)ws;                    ws += (size_t)n * sizeof(float);
        float2* pbuf = (float2*)ws;                   ws += (size_t)NB * SPLIT * BNODES * sizeof(float2);
        unsigned* pdeg = (unsigned*)ws;

        hipMemsetAsync(ovcnt, 0, 128, stream);
        k_bucket<<<NSEG, TB, 0, stream>>>(row, col, ovcnt, ovbuf, gbuf, E, NB);
        k_matvec<<<waveBlocks, TB, 0, stream>>>(x, w, z, n);
        k_deg_part<<<NB * SPLIT, TB, 0, stream>>>(gbuf, ovcnt, ovbuf, pdeg);
        k_deg_reduce<<<nodeBlocks, TB, 0, stream>>>(pdeg, z, dinv, zd, n);
        k_hop_part<<<NB * SPLIT, TB, 0, stream>>>(gbuf, ovcnt, ovbuf, zd, pbuf);
        k_mid_reduce<<<nodeBlocks, TB, 0, stream>>>(pbuf, zd, dinv, y1d, n);
        k_hop_part<<<NB * SPLIT, TB, 0, stream>>>(gbuf, ovcnt, ovbuf, y1d, pbuf);
        k_fin_reduce<<<nodeBlocks, TB, 0, stream>>>(pbuf, y1d, dinv, bias,
                                                    (float2*)d_out, n);
    } else {
        // R1 fallback: atomic scatter (known-correct)
        char* ws = (char*)d_ws;
        float2* z   = (float2*)ws; ws += (size_t)n * sizeof(float2);
        float2* y1  = (float2*)ws; ws += (size_t)n * sizeof(float2);
        float2* y2  = (float2*)ws; ws += (size_t)n * sizeof(float2);
        float*  dinv = (float*)ws; ws += (size_t)n * sizeof(float);
        unsigned int* deg = (unsigned int*)ws;

        hipMemsetAsync(deg, 0, (size_t)n * sizeof(unsigned int), stream);
        k_deg<<<edgeBlocks, TB, 0, stream>>>(col, deg, E);
        k_matvec<<<waveBlocks, TB, 0, stream>>>(x, w, z, n);
        k_dinv_init<<<nodeBlocks, TB, 0, stream>>>(deg, dinv, z, y1, n);
        k_edge<<<edgeBlocks, TB, 0, stream>>>(row, col, dinv, z, (float*)y1, E);
        k_selfloop<<<nodeBlocks, TB, 0, stream>>>(dinv, y1, y2, n);
        k_edge<<<edgeBlocks, TB, 0, stream>>>(row, col, dinv, y1, (float*)y2, E);
        k_final<<<nodeBlocks, TB, 0, stream>>>(y2, bias, (float2*)d_out, n);
    }
}